// Round 2
// baseline (3658.533 us; speedup 1.0000x reference)
//
#include <hip/hip_runtime.h>
#include <hip/hip_cooperative_groups.h>
#include <stdint.h>

namespace cg = cooperative_groups;

// DualPrimalEdgePooling on MI355X.
// Pipeline: radix-select threshold -> cooperative min-label CC (atomicMin +
// hooking + pointer jumping, exact fixpoint) -> root-rank scan ->
// counting-sort segmented mean (primal) -> pair bitmap + popcount-prefix
// ranking (dual) -> dual mean.

#define N_NODES 200000
#define N_EDGES 600000
#define FDIM 128
#define R_KEEP 300000u   // E - num_pool = NUM_KEEP; ascending-rank boundary

#define SC_B 0
#define SC_CLT 1
#define SC_T 2
#define SC_NEEDEQ 3
#define SC_TIECNT 4
#define SC_C 5
#define SC_W 6
#define SC_U 7
#define SC_VCNT 8
#define SC_CCFLAG 12
#define TIECAP 4096
#define SEG_CH 128
#define CC_BLOCKS 1024

__device__ __forceinline__ uint32_t f2ou(float f){
  uint32_t b = __float_as_uint(f);
  return (b & 0x80000000u) ? ~b : (b | 0x80000000u);
}
__device__ __forceinline__ int ld_ag(const int* p){
  return __hip_atomic_load(p, __ATOMIC_RELAXED, __HIP_MEMORY_SCOPE_AGENT);
}
__device__ __forceinline__ void st_ag(int* p, int v){
  __hip_atomic_store(p, v, __ATOMIC_RELAXED, __HIP_MEMORY_SCOPE_AGENT);
}

// ---- selection ----
__global__ void k_hist1(const float* att, uint32_t* hist){
  int e = blockIdx.x*256 + threadIdx.x;
  if(e < N_EDGES) atomicAdd(&hist[f2ou(att[e]) >> 16], 1u);
}
__global__ void k_hist2(const float* att, uint32_t* hist2, const uint32_t* sc){
  int e = blockIdx.x*256 + threadIdx.x;
  if(e >= N_EDGES) return;
  uint32_t u = f2ou(att[e]);
  if((u >> 16) == sc[SC_B]) atomicAdd(&hist2[u & 0xFFFFu], 1u);
}
__global__ __launch_bounds__(1024) void k_select_scan(const uint32_t* hist, uint32_t* sc, int phase){
  __shared__ uint32_t sm[1024];
  int t = threadIdx.x;
  uint32_t target = (phase == 1) ? (R_KEEP + 1u) : (R_KEEP + 1u - sc[SC_CLT]);
  uint32_t base = (uint32_t)t * 64u;
  uint32_t loc = 0;
  for(int k = 0; k < 64; k++) loc += hist[base + k];
  sm[t] = loc; __syncthreads();
  for(int off = 1; off < 1024; off <<= 1){
    uint32_t y = (t >= off) ? sm[t - off] : 0u;
    __syncthreads(); sm[t] += y; __syncthreads();
  }
  uint32_t incl = sm[t];
  uint32_t excl = incl - loc;
  if(excl < target && target <= incl){
    uint32_t c = excl; uint32_t bin = 0;
    for(int k = 0; k < 64; k++){
      c += hist[base + k];
      if(c >= target){ bin = base + k; break; }
    }
    if(phase == 1){ sc[SC_B] = bin; sc[SC_CLT] = c - hist[bin]; }
    else {
      uint32_t cumLE = sc[SC_CLT] + c;
      sc[SC_T] = (sc[SC_B] << 16) | bin;
      sc[SC_NEEDEQ] = cumLE - R_KEEP;
    }
  }
}
__global__ void k_mask(const float* att, uint8_t* mask, uint32_t* sc, uint32_t* tieIdx){
  int e = blockIdx.x*256 + threadIdx.x;
  if(e >= N_EDGES) return;
  uint32_t T = sc[SC_T];
  uint32_t u = f2ou(att[e]);
  mask[e] = (u > T) ? 1 : 0;
  if(u == T){
    uint32_t p = atomicAdd(&sc[SC_TIECNT], 1u);
    if(p < TIECAP) tieIdx[p] = (uint32_t)e;
  }
}
__global__ __launch_bounds__(1024) void k_tiesel(uint8_t* mask, const uint32_t* sc, const uint32_t* tieIdx){
  uint32_t m = sc[SC_TIECNT]; if(m > TIECAP) m = TIECAP;
  uint32_t need = sc[SC_NEEDEQ];
  for(uint32_t i = threadIdx.x; i < m; i += 1024){
    uint32_t mine = tieIdx[i];
    uint32_t r = 0;
    for(uint32_t j = 0; j < m; j++) r += (tieIdx[j] < mine) ? 1u : 0u;
    mask[mine] = (r < need) ? 1 : 0;   // stable argsort: smallest indices pooled
  }
}

// ---- cooperative connected components: min-label + hooking + jumping ----
// Fixpoint (no change in relax+jump phases) == labels[i] = min node id of
// component of i. Monotone (labels only decrease), commutative -> exact,
// schedule-independent result.
__global__ __launch_bounds__(256) void k_cc(const int* __restrict__ src, const int* __restrict__ dst,
                     const uint8_t* __restrict__ mask, int* labels, int* ccflag){
  cg::grid_group grid = cg::this_grid();
  const int T = CC_BLOCKS * 256;
  const int tid = blockIdx.x*256 + threadIdx.x;
  for(int i = tid; i < N_NODES; i += T) labels[i] = i;
  grid.sync();
  for(int iter = 0; iter < 64; ++iter){
    if(tid == 0) st_ag(ccflag, 0);
    grid.sync();
    int changed = 0;
    for(int e = tid; e < N_EDGES; e += T){
      if(!mask[e]) continue;
      int u = src[e], v = dst[e];
      if(u == v) continue;
      int lu = ld_ag(&labels[u]);
      int lv = ld_ag(&labels[v]);
      if(lu == lv) continue;
      int m = lu < lv ? lu : lv;
      int hn = lu < lv ? v : u;     // node holding the larger label
      int hl = lu < lv ? lv : lu;   // that label (itself a node id): hook it
      int old = atomicMin(&labels[hn], m);
      if(old > m) changed = 1;
      old = atomicMin(&labels[hl], m);
      if(old > m) changed = 1;
    }
    if(changed) st_ag(ccflag, 1);
    grid.sync();
    #pragma unroll
    for(int pass = 0; pass < 2; ++pass){
      int ch2 = 0;
      for(int i = tid; i < N_NODES; i += T){
        int li = ld_ag(&labels[i]);
        if(li == i) continue;
        int lj = ld_ag(&labels[li]);
        if(lj < li){
          int old = atomicMin(&labels[i], lj);
          if(old > lj) ch2 = 1;
        }
      }
      if(ch2) st_ag(ccflag, 1);
      grid.sync();
    }
    int f = __hip_atomic_load(ccflag, __ATOMIC_RELAXED, __HIP_MEMORY_SCOPE_AGENT);
    if(!f) break;         // uniform: read happens between two grid syncs
    grid.sync();          // protect next iteration's flag reset
  }
}
__global__ void k_flags(const int* labels, uint32_t* flags){
  int i = blockIdx.x*256 + threadIdx.x;
  if(i < N_NODES) flags[i] = (labels[i] == i) ? 1u : 0u;
}

// ---- generic exclusive scan (2048 items/block). MODE 0: identity, static len. MODE 1: popc, len = sc[SC_W] ----
template<int MODE>
__global__ void k_scan_reduce(const uint32_t* in, uint32_t* bsums, const uint32_t* sc, uint32_t staticLen){
  uint32_t n = (MODE == 1) ? sc[SC_W] : staticLen;
  uint32_t base = blockIdx.x*2048u + threadIdx.x*8u;
  uint32_t s = 0;
  #pragma unroll
  for(int k = 0; k < 8; k++){
    uint32_t idx = base + k;
    if(idx < n){ uint32_t v = in[idx]; if(MODE == 1) v = __popc(v); s += v; }
  }
  __shared__ uint32_t sm[256];
  sm[threadIdx.x] = s; __syncthreads();
  for(int off = 128; off > 0; off >>= 1){
    if((int)threadIdx.x < off) sm[threadIdx.x] += sm[threadIdx.x + off];
    __syncthreads();
  }
  if(threadIdx.x == 0) bsums[blockIdx.x] = sm[0];
}
__global__ __launch_bounds__(1024) void k_scan_top(uint32_t* bsums, int nb, uint32_t* sc, int extras){
  __shared__ uint32_t sm[1024];
  int t = threadIdx.x;
  uint32_t xs[4]; uint32_t tsum = 0;
  #pragma unroll
  for(int k = 0; k < 4; k++){ int idx = t*4 + k; xs[k] = (idx < nb) ? bsums[idx] : 0u; tsum += xs[k]; }
  sm[t] = tsum; __syncthreads();
  for(int off = 1; off < 1024; off <<= 1){
    uint32_t y = (t >= off) ? sm[t - off] : 0u;
    __syncthreads(); sm[t] += y; __syncthreads();
  }
  uint32_t run = sm[t] - tsum;
  #pragma unroll
  for(int k = 0; k < 4; k++){ int idx = t*4 + k; if(idx < nb) bsums[idx] = run; run += xs[k]; }
  uint32_t total = sm[1023];
  if(t == 0){
    if(extras == 1){ sc[SC_C] = total; uint64_t cc = (uint64_t)total*(uint64_t)total; sc[SC_W] = (uint32_t)((cc + 31ull) >> 5); }
    else if(extras == 2){ sc[SC_U] = total; }
  }
}
template<int MODE>
__global__ void k_scan_apply(const uint32_t* in, const uint32_t* bsums, uint32_t* out, const uint32_t* sc, uint32_t staticLen){
  uint32_t n = (MODE == 1) ? sc[SC_W] : staticLen;
  uint32_t base = blockIdx.x*2048u + threadIdx.x*8u;
  uint32_t xs[8]; uint32_t tsum = 0;
  #pragma unroll
  for(int k = 0; k < 8; k++){
    uint32_t idx = base + k; uint32_t v = 0;
    if(idx < n){ v = in[idx]; if(MODE == 1) v = __popc(v); }
    xs[k] = v; tsum += v;
  }
  __shared__ uint32_t sm[256];
  sm[threadIdx.x] = tsum; __syncthreads();
  for(int off = 1; off < 256; off <<= 1){
    uint32_t y = ((int)threadIdx.x >= off) ? sm[threadIdx.x - off] : 0u;
    __syncthreads(); sm[threadIdx.x] += y; __syncthreads();
  }
  uint32_t run = bsums[blockIdx.x] + sm[threadIdx.x] - tsum;
  #pragma unroll
  for(int k = 0; k < 8; k++){ uint32_t idx = base + k; if(idx < n) out[idx] = run; run += xs[k]; }
}

// ---- cluster ids ----
__global__ void k_cluster(const int* labels, const uint32_t* rank_, int* cluster_i, float* outC){
  int i = blockIdx.x*256 + threadIdx.x;
  if(i >= N_NODES) return;
  int c = (int)rank_[labels[i]];
  cluster_i[i] = c;
  outC[i] = (float)c;
}

// ---- wave-aggregated counting (giant component would serialize naive atomics) ----
__global__ void k_counts(const int* cluster_i, uint32_t* counts){
  int i = blockIdx.x*256 + threadIdx.x;
  int lane = threadIdx.x & 63;
  int c = (i < N_NODES) ? cluster_i[i] : -1;
  unsigned long long remaining = __ballot(i < N_NODES);
  while(remaining){
    int leader = __ffsll(remaining) - 1;
    int lc = __shfl(c, leader);
    unsigned long long grp = __ballot(c == lc) & remaining;
    if(lane == leader) atomicAdd(&counts[lc], (uint32_t)__popcll(grp));
    remaining &= ~grp;
  }
}
__global__ void k_scatter(const int* cluster_i, uint32_t* cursor, uint32_t* order){
  int i = blockIdx.x*256 + threadIdx.x;
  int lane = threadIdx.x & 63;
  int c = (i < N_NODES) ? cluster_i[i] : -1;
  unsigned long long remaining = __ballot(i < N_NODES);
  while(remaining){
    int leader = __ffsll(remaining) - 1;
    int lc = __shfl(c, leader);
    unsigned long long grp = __ballot(c == lc) & remaining;
    int b = 0;
    if(lane == leader) b = (int)atomicAdd(&cursor[lc], (uint32_t)__popcll(grp));
    b = __shfl(b, leader);
    if((grp >> lane) & 1ull){
      uint32_t sub = (uint32_t)__popcll(grp & ((1ull << lane) - 1ull));
      order[(uint32_t)b + sub] = (uint32_t)i;
    }
    remaining &= ~grp;
  }
}

// ---- segmented mean over sorted-by-cluster order ----
__global__ void k_segsum(const float* px, const uint32_t* order, const int* cluster_i, float* outP){
  int wid = (int)((blockIdx.x*blockDim.x + threadIdx.x) >> 6);
  int lane = threadIdx.x & 63;
  int start = wid * SEG_CH;
  if(start >= N_NODES) return;
  int end = start + SEG_CH; if(end > N_NODES) end = N_NODES;
  float ax = 0.f, ay = 0.f; int cur = -1;
  for(int j = start; j < end; j++){
    uint32_t i = order[j];
    int c = cluster_i[i];
    if(c != cur){
      if(cur >= 0){
        atomicAdd(&outP[(size_t)cur*FDIM + 2*lane], ax);
        atomicAdd(&outP[(size_t)cur*FDIM + 2*lane + 1], ay);
      }
      cur = c; ax = 0.f; ay = 0.f;
    }
    const float2* row = (const float2*)(px + (size_t)i*FDIM);
    float2 v = row[lane];
    ax += v.x; ay += v.y;
  }
  if(cur >= 0){
    atomicAdd(&outP[(size_t)cur*FDIM + 2*lane], ax);
    atomicAdd(&outP[(size_t)cur*FDIM + 2*lane + 1], ay);
  }
}
__global__ void k_pnorm(const uint32_t* counts, float* outP){
  int nw = (gridDim.x*blockDim.x) >> 6;
  int wid = (int)((blockIdx.x*blockDim.x + threadIdx.x) >> 6);
  int lane = threadIdx.x & 63;
  for(int r = wid; r < N_NODES; r += nw){
    uint32_t cnt = counts[r];
    if(cnt > 1){
      float fc = (float)cnt;
      float2* row = (float2*)(outP + (size_t)r*FDIM);
      float2 v = row[lane]; v.x /= fc; v.y /= fc; row[lane] = v;
    }
  }
}

// ---- edges + pair keys ----
__global__ void k_edges(const int* src, const int* dst, const int* cluster_i, uint32_t* sc,
                        float* outE, uint32_t* kc, uint32_t* vlist){
  int e = blockIdx.x*256 + threadIdx.x;
  if(e >= N_EDGES) return;
  int cu = cluster_i[src[e]];
  int cv = cluster_i[dst[e]];
  bool val = (cu != cv);
  outE[e] = val ? (float)cu : -1.0f;
  outE[N_EDGES + e] = val ? (float)cv : -1.0f;
  if(val){
    int a = cu < cv ? cu : cv, b = cu < cv ? cv : cu;
    uint32_t C = sc[SC_C];
    kc[e] = (uint32_t)a * C + (uint32_t)b;
    uint32_t p = atomicAdd(&sc[SC_VCNT], 1u);
    vlist[p] = (uint32_t)e;
  } else {
    kc[e] = 0xFFFFFFFFu;
  }
}
__global__ void k_bitmap(const uint32_t* kc, uint32_t* bitmap){
  int e = blockIdx.x*256 + threadIdx.x;
  if(e >= N_EDGES) return;
  uint32_t k = kc[e];
  if(k != 0xFFFFFFFFu) atomicOr(&bitmap[k >> 5], 1u << (k & 31u));
}
__global__ void k_dualacc(const float* dx, const uint32_t* vlist, const uint32_t* kc,
                          const uint32_t* bitmap, const uint32_t* wpref, const uint32_t* sc,
                          float* outD, uint32_t* dcnt){
  int nw = (gridDim.x*blockDim.x) >> 6;
  int wid = (int)((blockIdx.x*blockDim.x + threadIdx.x) >> 6);
  int lane = threadIdx.x & 63;
  uint32_t vc = sc[SC_VCNT];
  for(uint32_t k = (uint32_t)wid; k < vc; k += (uint32_t)nw){
    uint32_t e = vlist[k];
    uint32_t kcv = kc[e];
    uint32_t wi = kcv >> 5, bi = kcv & 31u;
    uint32_t r = wpref[wi] + __popc(bitmap[wi] & ((1u << bi) - 1u));
    const float2* row = (const float2*)(dx + (size_t)e*FDIM);
    float2 v = row[lane];
    atomicAdd(&outD[(size_t)r*FDIM + 2*lane], v.x);
    atomicAdd(&outD[(size_t)r*FDIM + 2*lane + 1], v.y);
    if(lane == 0) atomicAdd(&dcnt[r], 1u);
  }
}
__global__ void k_dualnorm(const uint32_t* dcnt, const uint32_t* sc, float* outD){
  int nw = (gridDim.x*blockDim.x) >> 6;
  int wid = (int)((blockIdx.x*blockDim.x + threadIdx.x) >> 6);
  int lane = threadIdx.x & 63;
  uint32_t U = sc[SC_U];
  for(uint32_t r = (uint32_t)wid; r < U; r += (uint32_t)nw){
    uint32_t cnt = dcnt[r];
    if(cnt > 1){
      float fc = (float)cnt;
      float2* row = (float2*)(outD + (size_t)r*FDIM);
      float2 v = row[lane]; v.x /= fc; v.y /= fc; row[lane] = v;
    }
  }
}

extern "C" void kernel_launch(void* const* d_in, const int* in_sizes, int n_in,
                              void* d_out, int out_size, void* d_ws, size_t ws_size,
                              hipStream_t stream){
  (void)in_sizes; (void)n_in; (void)out_size;
  const float* primal_x = (const float*)d_in[0];
  const float* dual_x   = (const float*)d_in[1];
  const float* att      = (const float*)d_in[2];
  const int*   pei      = (const int*)d_in[3];
  const int* src = pei;
  const int* dst = pei + N_EDGES;

  float* out  = (float*)d_out;
  float* outP = out;                                    // (N, F) means
  float* outD = out + (size_t)N_NODES*FDIM;             // (E, F) dual means
  float* outE = outD + (size_t)N_EDGES*FDIM;            // (2, E) edge index (as float)
  float* outC = outE + (size_t)2*N_EDGES;               // (N,) cluster (as float)

  uint32_t* w = (uint32_t*)d_ws;
  size_t words_avail = ws_size / 4;
  const size_t FIXED = 64 + 65536 + 65536 + (size_t)N_NODES + (size_t)N_EDGES
                     + TIECAP + 7*(size_t)N_NODES + ((size_t)N_EDGES + 3)/4
                     + 2*(size_t)N_EDGES + 4096;
  size_t wcap = (words_avail > FIXED) ? (words_avail - FIXED)/2 : 1;
  if(wcap > 8388608) wcap = 8388608;   // supports C up to 16384

  size_t o = 0;
  uint32_t* sc     = w;               o += 64;
  uint32_t* hist1  = w + o;           o += 65536;
  uint32_t* hist2  = w + o;           o += 65536;
  uint32_t* counts = w + o;           o += N_NODES;
  uint32_t* dcnt   = w + o;           o += N_EDGES;
  uint32_t* bitmap = w + o;           o += wcap;
  size_t zero_words = o;              // everything above zeroed per call
  uint32_t* tieIdx = w + o;           o += TIECAP;
  int* labels      = (int*)(w + o);   o += N_NODES;
  uint32_t* flags  = w + o;           o += N_NODES;
  uint32_t* rank_  = w + o;           o += N_NODES;
  uint32_t* cursor = w + o;           o += N_NODES;
  int* cluster_i   = (int*)(w + o);   o += N_NODES;
  uint32_t* order  = w + o;           o += N_NODES;
  uint8_t* mask    = (uint8_t*)(w + o); o += ((size_t)N_EDGES + 3)/4;
  uint32_t* kc     = w + o;           o += N_EDGES;
  uint32_t* vlist  = w + o;           o += N_EDGES;
  uint32_t* wpref  = w + o;           o += wcap;
  uint32_t* bsums  = w + o;           o += 4096;
  int* ccflag      = (int*)&sc[SC_CCFLAG];

  const int EB  = (N_EDGES + 255)/256;
  const int NB  = (N_NODES + 255)/256;
  const int NSB = (N_NODES + 2047)/2048;       // 98
  const int WSB = (int)((wcap + 2047)/2048);   // <= 4096

  hipMemsetAsync(out, 0, (size_t)(N_NODES + N_EDGES)*FDIM*sizeof(float), stream);
  hipMemsetAsync(w, 0, zero_words*sizeof(uint32_t), stream);

  // top-K selection
  k_hist1<<<EB,256,0,stream>>>(att, hist1);
  k_select_scan<<<1,1024,0,stream>>>(hist1, sc, 1);
  k_hist2<<<EB,256,0,stream>>>(att, hist2, sc);
  k_select_scan<<<1,1024,0,stream>>>(hist2, sc, 2);
  k_mask<<<EB,256,0,stream>>>(att, mask, sc, tieIdx);
  k_tiesel<<<1,1024,0,stream>>>(mask, sc, tieIdx);
  // connected components: cooperative min-label propagation to exact fixpoint
  {
    void* kargs[] = { (void*)&src, (void*)&dst, (void*)&mask, (void*)&labels, (void*)&ccflag };
    hipLaunchCooperativeKernel((void*)k_cc, dim3(CC_BLOCKS), dim3(256), kargs, 0, stream);
  }
  k_flags<<<NB,256,0,stream>>>(labels, flags);
  // compact labels -> cluster ids
  k_scan_reduce<0><<<NSB,256,0,stream>>>(flags, bsums, sc, N_NODES);
  k_scan_top<<<1,1024,0,stream>>>(bsums, NSB, sc, 1);
  k_scan_apply<0><<<NSB,256,0,stream>>>(flags, bsums, rank_, sc, N_NODES);
  k_cluster<<<NB,256,0,stream>>>(labels, rank_, cluster_i, outC);
  // primal mean via counting sort + contiguous segmented reduction
  k_counts<<<NB,256,0,stream>>>(cluster_i, counts);
  k_scan_reduce<0><<<NSB,256,0,stream>>>(counts, bsums, sc, N_NODES);
  k_scan_top<<<1,1024,0,stream>>>(bsums, NSB, sc, 0);
  k_scan_apply<0><<<NSB,256,0,stream>>>(counts, bsums, cursor, sc, N_NODES);
  k_scatter<<<NB,256,0,stream>>>(cluster_i, cursor, order);
  {
    int segw = (N_NODES + SEG_CH - 1)/SEG_CH;
    int segb = (segw + 3)/4;
    k_segsum<<<segb,256,0,stream>>>(primal_x, order, cluster_i, outP);
  }
  k_pnorm<<<512,256,0,stream>>>(counts, outP);
  // edges + dual-pair ranking via bitmap popcount-prefix
  k_edges<<<EB,256,0,stream>>>(src, dst, cluster_i, sc, outE, kc, vlist);
  k_bitmap<<<EB,256,0,stream>>>(kc, bitmap);
  k_scan_reduce<1><<<WSB,256,0,stream>>>(bitmap, bsums, sc, 0);
  k_scan_top<<<1,1024,0,stream>>>(bsums, WSB, sc, 2);
  k_scan_apply<1><<<WSB,256,0,stream>>>(bitmap, bsums, wpref, sc, 0);
  k_dualacc<<<1024,256,0,stream>>>(dual_x, vlist, kc, bitmap, wpref, sc, outD, dcnt);
  k_dualnorm<<<256,256,0,stream>>>(dcnt, sc, outD);
}

// Round 3
// 1835.987 us; speedup vs baseline: 1.9927x; 1.9927x over previous
//
#include <hip/hip_runtime.h>
#include <stdint.h>

// DualPrimalEdgePooling on MI355X.
// Pipeline: radix-select threshold -> ECL-CC union-find (cached finds +
// CAS-verified min-hooking, 3 dispatches) -> root-rank scan ->
// counting-sort segmented mean (primal) -> pair bitmap + popcount-prefix
// ranking (dual) -> dual mean.

#define N_NODES 200000
#define N_EDGES 600000
#define FDIM 128
#define R_KEEP 300000u   // E - num_pool = NUM_KEEP; ascending-rank boundary

#define SC_B 0
#define SC_CLT 1
#define SC_T 2
#define SC_NEEDEQ 3
#define SC_TIECNT 4
#define SC_C 5
#define SC_W 6
#define SC_U 7
#define SC_VCNT 8
#define TIECAP 4096
#define SEG_CH 128

__device__ __forceinline__ uint32_t f2ou(float f){
  uint32_t b = __float_as_uint(f);
  return (b & 0x80000000u) ? ~b : (b | 0x80000000u);
}

// ---- selection ----
__global__ void k_hist1(const float* att, uint32_t* hist){
  int e = blockIdx.x*256 + threadIdx.x;
  if(e < N_EDGES) atomicAdd(&hist[f2ou(att[e]) >> 16], 1u);
}
__global__ void k_hist2(const float* att, uint32_t* hist2, const uint32_t* sc){
  int e = blockIdx.x*256 + threadIdx.x;
  if(e >= N_EDGES) return;
  uint32_t u = f2ou(att[e]);
  if((u >> 16) == sc[SC_B]) atomicAdd(&hist2[u & 0xFFFFu], 1u);
}
__global__ __launch_bounds__(1024) void k_select_scan(const uint32_t* hist, uint32_t* sc, int phase){
  __shared__ uint32_t sm[1024];
  int t = threadIdx.x;
  uint32_t target = (phase == 1) ? (R_KEEP + 1u) : (R_KEEP + 1u - sc[SC_CLT]);
  uint32_t base = (uint32_t)t * 64u;
  uint32_t loc = 0;
  for(int k = 0; k < 64; k++) loc += hist[base + k];
  sm[t] = loc; __syncthreads();
  for(int off = 1; off < 1024; off <<= 1){
    uint32_t y = (t >= off) ? sm[t - off] : 0u;
    __syncthreads(); sm[t] += y; __syncthreads();
  }
  uint32_t incl = sm[t];
  uint32_t excl = incl - loc;
  if(excl < target && target <= incl){
    uint32_t c = excl; uint32_t bin = 0;
    for(int k = 0; k < 64; k++){
      c += hist[base + k];
      if(c >= target){ bin = base + k; break; }
    }
    if(phase == 1){ sc[SC_B] = bin; sc[SC_CLT] = c - hist[bin]; }
    else {
      uint32_t cumLE = sc[SC_CLT] + c;
      sc[SC_T] = (sc[SC_B] << 16) | bin;
      sc[SC_NEEDEQ] = cumLE - R_KEEP;
    }
  }
}
__global__ void k_mask(const float* att, uint8_t* mask, uint32_t* sc, uint32_t* tieIdx){
  int e = blockIdx.x*256 + threadIdx.x;
  if(e >= N_EDGES) return;
  uint32_t T = sc[SC_T];
  uint32_t u = f2ou(att[e]);
  mask[e] = (u > T) ? 1 : 0;
  if(u == T){
    uint32_t p = atomicAdd(&sc[SC_TIECNT], 1u);
    if(p < TIECAP) tieIdx[p] = (uint32_t)e;
  }
}
__global__ __launch_bounds__(1024) void k_tiesel(uint8_t* mask, const uint32_t* sc, const uint32_t* tieIdx){
  uint32_t m = sc[SC_TIECNT]; if(m > TIECAP) m = TIECAP;
  uint32_t need = sc[SC_NEEDEQ];
  for(uint32_t i = threadIdx.x; i < m; i += 1024){
    uint32_t mine = tieIdx[i];
    uint32_t r = 0;
    for(uint32_t j = 0; j < m; j++) r += (tieIdx[j] < mine) ? 1u : 0u;
    mask[mine] = (r < need) ? 1 : 0;   // stable argsort: smallest indices pooled
  }
}

// ---- ECL-CC style connected components --------------------------------
// Invariant: any value ever stored at label[x] is <= x and lies in x's
// component => chases strictly decrease and terminate even with stale
// (non-coherent L2) reads. atomicCAS at device scope is the coherence
// point that verifies hooks; kernel boundaries flush L2 between phases.
__device__ __forceinline__ int rep_cc(int* label, int v){
  int p = label[v];
  if(p == v) return v;
  int prev = v;
  int next = label[p];
  while(next != p){
    label[prev] = next;   // path compression: plain store (hint, safe if lost)
    prev = p;
    p = next;
    next = label[p];
  }
  return p;
}
__global__ void k_cc_seed(const int* src, const int* dst, const uint8_t* mask, int* label){
  int e = blockIdx.x*256 + threadIdx.x;
  if(e >= N_EDGES) return;
  if(!mask[e]) return;
  int u = src[e], v = dst[e];
  if(u == v) return;
  if(u < v) atomicMin(&label[v], u);
  else      atomicMin(&label[u], v);
}
__global__ void k_cc_hook(const int* src, const int* dst, const uint8_t* mask, int* label){
  int e = blockIdx.x*256 + threadIdx.x;
  if(e >= N_EDGES) return;
  if(!mask[e]) return;
  int u = src[e], v = dst[e];
  if(u == v) return;
  int ru = rep_cc(label, u);
  int rv = rep_cc(label, v);
  while(ru != rv){
    int hi = ru > rv ? ru : rv;
    int lo = (hi == ru) ? rv : ru;
    int old = atomicCAS(&label[hi], hi, lo);
    if(old == hi) break;             // hooked hi under lo
    ru = rep_cc(label, old);         // fresh value from coherence point
    rv = lo;
  }
}
__global__ void k_cc_init(int* label){
  int i = blockIdx.x*256 + threadIdx.x;
  if(i < N_NODES) label[i] = i;
}
__global__ void k_cc_flatten(int* label, uint32_t* flags){
  int i = blockIdx.x*256 + threadIdx.x;
  if(i >= N_NODES) return;
  int p = label[i];
  int q = label[p];
  while(q != p){ p = q; q = label[p]; }
  label[i] = p;
  flags[i] = (p == i) ? 1u : 0u;
}

// ---- generic exclusive scan (2048 items/block). MODE 0: identity, static len. MODE 1: popc, len = sc[SC_W] ----
template<int MODE>
__global__ void k_scan_reduce(const uint32_t* in, uint32_t* bsums, const uint32_t* sc, uint32_t staticLen){
  uint32_t n = (MODE == 1) ? sc[SC_W] : staticLen;
  uint32_t base = blockIdx.x*2048u + threadIdx.x*8u;
  uint32_t s = 0;
  #pragma unroll
  for(int k = 0; k < 8; k++){
    uint32_t idx = base + k;
    if(idx < n){ uint32_t v = in[idx]; if(MODE == 1) v = __popc(v); s += v; }
  }
  __shared__ uint32_t sm[256];
  sm[threadIdx.x] = s; __syncthreads();
  for(int off = 128; off > 0; off >>= 1){
    if((int)threadIdx.x < off) sm[threadIdx.x] += sm[threadIdx.x + off];
    __syncthreads();
  }
  if(threadIdx.x == 0) bsums[blockIdx.x] = sm[0];
}
__global__ __launch_bounds__(1024) void k_scan_top(uint32_t* bsums, int nb, uint32_t* sc, int extras){
  __shared__ uint32_t sm[1024];
  int t = threadIdx.x;
  uint32_t xs[4]; uint32_t tsum = 0;
  #pragma unroll
  for(int k = 0; k < 4; k++){ int idx = t*4 + k; xs[k] = (idx < nb) ? bsums[idx] : 0u; tsum += xs[k]; }
  sm[t] = tsum; __syncthreads();
  for(int off = 1; off < 1024; off <<= 1){
    uint32_t y = (t >= off) ? sm[t - off] : 0u;
    __syncthreads(); sm[t] += y; __syncthreads();
  }
  uint32_t run = sm[t] - tsum;
  #pragma unroll
  for(int k = 0; k < 4; k++){ int idx = t*4 + k; if(idx < nb) bsums[idx] = run; run += xs[k]; }
  uint32_t total = sm[1023];
  if(t == 0){
    if(extras == 1){ sc[SC_C] = total; uint64_t cc = (uint64_t)total*(uint64_t)total; sc[SC_W] = (uint32_t)((cc + 31ull) >> 5); }
    else if(extras == 2){ sc[SC_U] = total; }
  }
}
template<int MODE>
__global__ void k_scan_apply(const uint32_t* in, const uint32_t* bsums, uint32_t* out, const uint32_t* sc, uint32_t staticLen){
  uint32_t n = (MODE == 1) ? sc[SC_W] : staticLen;
  uint32_t base = blockIdx.x*2048u + threadIdx.x*8u;
  uint32_t xs[8]; uint32_t tsum = 0;
  #pragma unroll
  for(int k = 0; k < 8; k++){
    uint32_t idx = base + k; uint32_t v = 0;
    if(idx < n){ v = in[idx]; if(MODE == 1) v = __popc(v); }
    xs[k] = v; tsum += v;
  }
  __shared__ uint32_t sm[256];
  sm[threadIdx.x] = tsum; __syncthreads();
  for(int off = 1; off < 256; off <<= 1){
    uint32_t y = ((int)threadIdx.x >= off) ? sm[threadIdx.x - off] : 0u;
    __syncthreads(); sm[threadIdx.x] += y; __syncthreads();
  }
  uint32_t run = bsums[blockIdx.x] + sm[threadIdx.x] - tsum;
  #pragma unroll
  for(int k = 0; k < 8; k++){ uint32_t idx = base + k; if(idx < n) out[idx] = run; run += xs[k]; }
}

// ---- cluster ids ----
__global__ void k_cluster(const int* labels, const uint32_t* rank_, int* cluster_i, float* outC){
  int i = blockIdx.x*256 + threadIdx.x;
  if(i >= N_NODES) return;
  int c = (int)rank_[labels[i]];
  cluster_i[i] = c;
  outC[i] = (float)c;
}

// ---- wave-aggregated counting (giant component would serialize naive atomics) ----
__global__ void k_counts(const int* cluster_i, uint32_t* counts){
  int i = blockIdx.x*256 + threadIdx.x;
  int lane = threadIdx.x & 63;
  int c = (i < N_NODES) ? cluster_i[i] : -1;
  unsigned long long remaining = __ballot(i < N_NODES);
  while(remaining){
    int leader = __ffsll(remaining) - 1;
    int lc = __shfl(c, leader);
    unsigned long long grp = __ballot(c == lc) & remaining;
    if(lane == leader) atomicAdd(&counts[lc], (uint32_t)__popcll(grp));
    remaining &= ~grp;
  }
}
__global__ void k_scatter(const int* cluster_i, uint32_t* cursor, uint32_t* order){
  int i = blockIdx.x*256 + threadIdx.x;
  int lane = threadIdx.x & 63;
  int c = (i < N_NODES) ? cluster_i[i] : -1;
  unsigned long long remaining = __ballot(i < N_NODES);
  while(remaining){
    int leader = __ffsll(remaining) - 1;
    int lc = __shfl(c, leader);
    unsigned long long grp = __ballot(c == lc) & remaining;
    int b = 0;
    if(lane == leader) b = (int)atomicAdd(&cursor[lc], (uint32_t)__popcll(grp));
    b = __shfl(b, leader);
    if((grp >> lane) & 1ull){
      uint32_t sub = (uint32_t)__popcll(grp & ((1ull << lane) - 1ull));
      order[(uint32_t)b + sub] = (uint32_t)i;
    }
    remaining &= ~grp;
  }
}

// ---- segmented mean over sorted-by-cluster order ----
__global__ void k_segsum(const float* px, const uint32_t* order, const int* cluster_i, float* outP){
  int wid = (int)((blockIdx.x*blockDim.x + threadIdx.x) >> 6);
  int lane = threadIdx.x & 63;
  int start = wid * SEG_CH;
  if(start >= N_NODES) return;
  int end = start + SEG_CH; if(end > N_NODES) end = N_NODES;
  float ax = 0.f, ay = 0.f; int cur = -1;
  for(int j = start; j < end; j++){
    uint32_t i = order[j];
    int c = cluster_i[i];
    if(c != cur){
      if(cur >= 0){
        atomicAdd(&outP[(size_t)cur*FDIM + 2*lane], ax);
        atomicAdd(&outP[(size_t)cur*FDIM + 2*lane + 1], ay);
      }
      cur = c; ax = 0.f; ay = 0.f;
    }
    const float2* row = (const float2*)(px + (size_t)i*FDIM);
    float2 v = row[lane];
    ax += v.x; ay += v.y;
  }
  if(cur >= 0){
    atomicAdd(&outP[(size_t)cur*FDIM + 2*lane], ax);
    atomicAdd(&outP[(size_t)cur*FDIM + 2*lane + 1], ay);
  }
}
__global__ void k_pnorm(const uint32_t* counts, float* outP){
  int nw = (gridDim.x*blockDim.x) >> 6;
  int wid = (int)((blockIdx.x*blockDim.x + threadIdx.x) >> 6);
  int lane = threadIdx.x & 63;
  for(int r = wid; r < N_NODES; r += nw){
    uint32_t cnt = counts[r];
    if(cnt > 1){
      float fc = (float)cnt;
      float2* row = (float2*)(outP + (size_t)r*FDIM);
      float2 v = row[lane]; v.x /= fc; v.y /= fc; row[lane] = v;
    }
  }
}

// ---- edges + pair keys ----
__global__ void k_edges(const int* src, const int* dst, const int* cluster_i, uint32_t* sc,
                        float* outE, uint32_t* kc, uint32_t* vlist){
  int e = blockIdx.x*256 + threadIdx.x;
  if(e >= N_EDGES) return;
  int cu = cluster_i[src[e]];
  int cv = cluster_i[dst[e]];
  bool val = (cu != cv);
  outE[e] = val ? (float)cu : -1.0f;
  outE[N_EDGES + e] = val ? (float)cv : -1.0f;
  if(val){
    int a = cu < cv ? cu : cv, b = cu < cv ? cv : cu;
    uint32_t C = sc[SC_C];
    kc[e] = (uint32_t)a * C + (uint32_t)b;
    uint32_t p = atomicAdd(&sc[SC_VCNT], 1u);
    vlist[p] = (uint32_t)e;
  } else {
    kc[e] = 0xFFFFFFFFu;
  }
}
__global__ void k_bitmap(const uint32_t* kc, uint32_t* bitmap){
  int e = blockIdx.x*256 + threadIdx.x;
  if(e >= N_EDGES) return;
  uint32_t k = kc[e];
  if(k != 0xFFFFFFFFu) atomicOr(&bitmap[k >> 5], 1u << (k & 31u));
}
__global__ void k_dualacc(const float* dx, const uint32_t* vlist, const uint32_t* kc,
                          const uint32_t* bitmap, const uint32_t* wpref, const uint32_t* sc,
                          float* outD, uint32_t* dcnt){
  int nw = (gridDim.x*blockDim.x) >> 6;
  int wid = (int)((blockIdx.x*blockDim.x + threadIdx.x) >> 6);
  int lane = threadIdx.x & 63;
  uint32_t vc = sc[SC_VCNT];
  for(uint32_t k = (uint32_t)wid; k < vc; k += (uint32_t)nw){
    uint32_t e = vlist[k];
    uint32_t kcv = kc[e];
    uint32_t wi = kcv >> 5, bi = kcv & 31u;
    uint32_t r = wpref[wi] + __popc(bitmap[wi] & ((1u << bi) - 1u));
    const float2* row = (const float2*)(dx + (size_t)e*FDIM);
    float2 v = row[lane];
    atomicAdd(&outD[(size_t)r*FDIM + 2*lane], v.x);
    atomicAdd(&outD[(size_t)r*FDIM + 2*lane + 1], v.y);
    if(lane == 0) atomicAdd(&dcnt[r], 1u);
  }
}
__global__ void k_dualnorm(const uint32_t* dcnt, const uint32_t* sc, float* outD){
  int nw = (gridDim.x*blockDim.x) >> 6;
  int wid = (int)((blockIdx.x*blockDim.x + threadIdx.x) >> 6);
  int lane = threadIdx.x & 63;
  uint32_t U = sc[SC_U];
  for(uint32_t r = (uint32_t)wid; r < U; r += (uint32_t)nw){
    uint32_t cnt = dcnt[r];
    if(cnt > 1){
      float fc = (float)cnt;
      float2* row = (float2*)(outD + (size_t)r*FDIM);
      float2 v = row[lane]; v.x /= fc; v.y /= fc; row[lane] = v;
    }
  }
}

extern "C" void kernel_launch(void* const* d_in, const int* in_sizes, int n_in,
                              void* d_out, int out_size, void* d_ws, size_t ws_size,
                              hipStream_t stream){
  (void)in_sizes; (void)n_in; (void)out_size;
  const float* primal_x = (const float*)d_in[0];
  const float* dual_x   = (const float*)d_in[1];
  const float* att      = (const float*)d_in[2];
  const int*   pei      = (const int*)d_in[3];
  const int* src = pei;
  const int* dst = pei + N_EDGES;

  float* out  = (float*)d_out;
  float* outP = out;                                    // (N, F) means
  float* outD = out + (size_t)N_NODES*FDIM;             // (E, F) dual means
  float* outE = outD + (size_t)N_EDGES*FDIM;            // (2, E) edge index (as float)
  float* outC = outE + (size_t)2*N_EDGES;               // (N,) cluster (as float)

  uint32_t* w = (uint32_t*)d_ws;
  size_t words_avail = ws_size / 4;
  const size_t FIXED = 64 + 65536 + 65536 + (size_t)N_NODES + (size_t)N_EDGES
                     + TIECAP + 7*(size_t)N_NODES + ((size_t)N_EDGES + 3)/4
                     + 2*(size_t)N_EDGES + 4096;
  size_t wcap = (words_avail > FIXED) ? (words_avail - FIXED)/2 : 1;
  if(wcap > 8388608) wcap = 8388608;   // supports C up to 16384

  size_t o = 0;
  uint32_t* sc     = w;               o += 64;
  uint32_t* hist1  = w + o;           o += 65536;
  uint32_t* hist2  = w + o;           o += 65536;
  uint32_t* counts = w + o;           o += N_NODES;
  uint32_t* dcnt   = w + o;           o += N_EDGES;
  uint32_t* bitmap = w + o;           o += wcap;
  size_t zero_words = o;              // everything above zeroed per call
  uint32_t* tieIdx = w + o;           o += TIECAP;
  int* labels      = (int*)(w + o);   o += N_NODES;
  uint32_t* flags  = w + o;           o += N_NODES;
  uint32_t* rank_  = w + o;           o += N_NODES;
  uint32_t* cursor = w + o;           o += N_NODES;
  int* cluster_i   = (int*)(w + o);   o += N_NODES;
  uint32_t* order  = w + o;           o += N_NODES;
  uint8_t* mask    = (uint8_t*)(w + o); o += ((size_t)N_EDGES + 3)/4;
  uint32_t* kc     = w + o;           o += N_EDGES;
  uint32_t* vlist  = w + o;           o += N_EDGES;
  uint32_t* wpref  = w + o;           o += wcap;
  uint32_t* bsums  = w + o;           o += 4096;

  const int EB  = (N_EDGES + 255)/256;
  const int NB  = (N_NODES + 255)/256;
  const int NSB = (N_NODES + 2047)/2048;       // 98
  const int WSB = (int)((wcap + 2047)/2048);   // <= 4096

  hipMemsetAsync(out, 0, (size_t)(N_NODES + N_EDGES)*FDIM*sizeof(float), stream);
  hipMemsetAsync(w, 0, zero_words*sizeof(uint32_t), stream);

  // top-K selection
  k_hist1<<<EB,256,0,stream>>>(att, hist1);
  k_select_scan<<<1,1024,0,stream>>>(hist1, sc, 1);
  k_hist2<<<EB,256,0,stream>>>(att, hist2, sc);
  k_select_scan<<<1,1024,0,stream>>>(hist2, sc, 2);
  k_mask<<<EB,256,0,stream>>>(att, mask, sc, tieIdx);
  k_tiesel<<<1,1024,0,stream>>>(mask, sc, tieIdx);
  // connected components: ECL-CC (cached finds, CAS-verified min hooking)
  k_cc_init<<<NB,256,0,stream>>>(labels);
  k_cc_seed<<<EB,256,0,stream>>>(src, dst, mask, labels);
  k_cc_hook<<<EB,256,0,stream>>>(src, dst, mask, labels);
  k_cc_flatten<<<NB,256,0,stream>>>(labels, flags);
  // compact labels -> cluster ids
  k_scan_reduce<0><<<NSB,256,0,stream>>>(flags, bsums, sc, N_NODES);
  k_scan_top<<<1,1024,0,stream>>>(bsums, NSB, sc, 1);
  k_scan_apply<0><<<NSB,256,0,stream>>>(flags, bsums, rank_, sc, N_NODES);
  k_cluster<<<NB,256,0,stream>>>(labels, rank_, cluster_i, outC);
  // primal mean via counting sort + contiguous segmented reduction
  k_counts<<<NB,256,0,stream>>>(cluster_i, counts);
  k_scan_reduce<0><<<NSB,256,0,stream>>>(counts, bsums, sc, N_NODES);
  k_scan_top<<<1,1024,0,stream>>>(bsums, NSB, sc, 0);
  k_scan_apply<0><<<NSB,256,0,stream>>>(counts, bsums, cursor, sc, N_NODES);
  k_scatter<<<NB,256,0,stream>>>(cluster_i, cursor, order);
  {
    int segw = (N_NODES + SEG_CH - 1)/SEG_CH;
    int segb = (segw + 3)/4;
    k_segsum<<<segb,256,0,stream>>>(primal_x, order, cluster_i, outP);
  }
  k_pnorm<<<512,256,0,stream>>>(counts, outP);
  // edges + dual-pair ranking via bitmap popcount-prefix
  k_edges<<<EB,256,0,stream>>>(src, dst, cluster_i, sc, outE, kc, vlist);
  k_bitmap<<<EB,256,0,stream>>>(kc, bitmap);
  k_scan_reduce<1><<<WSB,256,0,stream>>>(bitmap, bsums, sc, 0);
  k_scan_top<<<1,1024,0,stream>>>(bsums, WSB, sc, 2);
  k_scan_apply<1><<<WSB,256,0,stream>>>(bitmap, bsums, wpref, sc, 0);
  k_dualacc<<<1024,256,0,stream>>>(dual_x, vlist, kc, bitmap, wpref, sc, outD, dcnt);
  k_dualnorm<<<256,256,0,stream>>>(dcnt, sc, outD);
}

// Round 4
// 1176.161 us; speedup vs baseline: 3.1106x; 1.5610x over previous
//
#include <hip/hip_runtime.h>
#include <stdint.h>

// DualPrimalEdgePooling on MI355X.
// Pipeline: radix-select threshold -> worklist min-label CC (loop-free
// hooking relax + pointer-jump rounds, shrinking worklist) -> root-rank
// scan -> counting-sort segmented mean (primal) -> pair bitmap +
// popcount-prefix ranking (dual) -> dual mean.

#define N_NODES 200000
#define N_EDGES 600000
#define FDIM 128
#define R_KEEP 300000u   // E - num_pool = NUM_KEEP; ascending-rank boundary

#define SC_B 0
#define SC_CLT 1
#define SC_T 2
#define SC_NEEDEQ 3
#define SC_TIECNT 4
#define SC_C 5
#define SC_W 6
#define SC_U 7
#define SC_VCNT 8
#define SC_WLA 9
#define SC_WLB 10
#define TIECAP 4096
#define SEG_CH 128
#define WLCAP 300800
#define CC_ROUNDS 12

__device__ __forceinline__ uint32_t f2ou(float f){
  uint32_t b = __float_as_uint(f);
  return (b & 0x80000000u) ? ~b : (b | 0x80000000u);
}

// ---- selection ----
__global__ void k_hist1(const float* att, uint32_t* hist){
  int e = blockIdx.x*256 + threadIdx.x;
  if(e < N_EDGES) atomicAdd(&hist[f2ou(att[e]) >> 16], 1u);
}
__global__ void k_hist2(const float* att, uint32_t* hist2, const uint32_t* sc){
  int e = blockIdx.x*256 + threadIdx.x;
  if(e >= N_EDGES) return;
  uint32_t u = f2ou(att[e]);
  if((u >> 16) == sc[SC_B]) atomicAdd(&hist2[u & 0xFFFFu], 1u);
}
__global__ __launch_bounds__(1024) void k_select_scan(const uint32_t* hist, uint32_t* sc, int phase){
  __shared__ uint32_t sm[1024];
  int t = threadIdx.x;
  uint32_t target = (phase == 1) ? (R_KEEP + 1u) : (R_KEEP + 1u - sc[SC_CLT]);
  uint32_t base = (uint32_t)t * 64u;
  uint32_t loc = 0;
  for(int k = 0; k < 64; k++) loc += hist[base + k];
  sm[t] = loc; __syncthreads();
  for(int off = 1; off < 1024; off <<= 1){
    uint32_t y = (t >= off) ? sm[t - off] : 0u;
    __syncthreads(); sm[t] += y; __syncthreads();
  }
  uint32_t incl = sm[t];
  uint32_t excl = incl - loc;
  if(excl < target && target <= incl){
    uint32_t c = excl; uint32_t bin = 0;
    for(int k = 0; k < 64; k++){
      c += hist[base + k];
      if(c >= target){ bin = base + k; break; }
    }
    if(phase == 1){ sc[SC_B] = bin; sc[SC_CLT] = c - hist[bin]; }
    else {
      uint32_t cumLE = sc[SC_CLT] + c;
      sc[SC_T] = (sc[SC_B] << 16) | bin;
      sc[SC_NEEDEQ] = cumLE - R_KEEP;
    }
  }
}

// ---- CC: init, seed (selection fused), loop-free relax rounds, jump, flatten ----
__global__ void k_cc_init(int* L){
  int i = blockIdx.x*256 + threadIdx.x;
  if(i < N_NODES) L[i] = i;
}
// pooled edges (att > T): seed atomicMin + append to worklist; ties recorded
__global__ void k_seed(const float* att, const int* src, const int* dst, uint32_t* sc,
                       uint32_t* tieIdx, int* L, uint2* wl){
  int e = blockIdx.x*256 + threadIdx.x;
  int lane = threadIdx.x & 63;
  bool app = false; int u = 0, v = 0;
  if(e < N_EDGES){
    uint32_t T = sc[SC_T];
    uint32_t ub = f2ou(att[e]);
    if(ub > T){
      u = src[e]; v = dst[e];
      if(u != v){
        int m = u < v ? u : v, hi = u ^ v ^ m;
        atomicMin(&L[hi], m);
        app = true;
      }
    } else if(ub == T){
      uint32_t p = atomicAdd(&sc[SC_TIECNT], 1u);
      if(p < TIECAP) tieIdx[p] = (uint32_t)e;
    }
  }
  unsigned long long grp = __ballot(app);
  if(grp){
    int leader = __ffsll(grp) - 1;
    uint32_t base = 0;
    if(lane == leader) base = atomicAdd(&sc[SC_WLA], (uint32_t)__popcll(grp));
    base = (uint32_t)__shfl((int)base, leader);
    if(app){
      uint32_t off = (uint32_t)__popcll(grp & ((1ull << lane) - 1ull));
      wl[base + off] = make_uint2((uint32_t)(u < v ? u : v), (uint32_t)(u > v ? u : v));
    }
  }
}
__global__ __launch_bounds__(1024) void k_tiesel(uint32_t* sc, const uint32_t* tieIdx,
                        const int* src, const int* dst, int* L, uint2* wl){
  uint32_t m = sc[SC_TIECNT]; if(m > TIECAP) m = TIECAP;
  uint32_t need = sc[SC_NEEDEQ];
  int lane = threadIdx.x & 63;
  for(uint32_t i0 = 0; i0 < m; i0 += 1024){
    uint32_t i = i0 + threadIdx.x;
    bool app = false; int u = 0, v = 0;
    if(i < m){
      uint32_t mine = tieIdx[i];
      uint32_t r = 0;
      for(uint32_t j = 0; j < m; j++) r += (tieIdx[j] < mine) ? 1u : 0u;
      if(r < need){   // stable argsort: smallest indices pooled
        u = src[mine]; v = dst[mine];
        if(u != v){ int mm = u < v ? u : v, hi = u ^ v ^ mm; atomicMin(&L[hi], mm); app = true; }
      }
    }
    unsigned long long grp = __ballot(app);
    if(grp){
      int leader = __ffsll(grp) - 1;
      uint32_t base = 0;
      if(lane == leader) base = atomicAdd(&sc[SC_WLA], (uint32_t)__popcll(grp));
      base = (uint32_t)__shfl((int)base, leader);
      if(app){
        uint32_t off = (uint32_t)__popcll(grp & ((1ull << lane) - 1ull));
        wl[base + off] = make_uint2((uint32_t)(u < v ? u : v), (uint32_t)(u > v ? u : v));
      }
    }
  }
}
// loop-free relax: 3-level chase (plain loads), one-shot hooking atomicMin,
// survivors re-appended. Stale reads are >= true value (monotone) => safe.
__global__ __launch_bounds__(256) void k_relax(const uint2* wl_in, uint2* wl_out, int* L,
                       uint32_t* sc, int inSlot, int outSlot){
  uint32_t n = sc[inSlot];
  int lane = threadIdx.x & 63;
  for(uint32_t base = blockIdx.x*256u; base < n; base += gridDim.x*256u){
    uint32_t idx = base + threadIdx.x;
    bool active = idx < n;
    int lu = 0, lv = 0;
    if(active){
      uint2 ed = wl_in[idx];
      lu = L[ed.x]; lu = L[lu]; lu = L[lu];
      lv = L[ed.y]; lv = L[lv]; lv = L[lv];
      active = (lu != lv);
      if(active){
        int m = lu < lv ? lu : lv, hi = lu ^ lv ^ m;
        atomicMin(&L[hi], m);
      }
    }
    unsigned long long grp = __ballot(active);
    if(grp){
      int leader = __ffsll(grp) - 1;
      uint32_t b = 0;
      if(lane == leader) b = atomicAdd(&sc[outSlot], (uint32_t)__popcll(grp));
      b = (uint32_t)__shfl((int)b, leader);
      if(active){
        uint32_t off = (uint32_t)__popcll(grp & ((1ull << lane) - 1ull));
        wl_out[b + off] = make_uint2((uint32_t)(lu < lv ? lu : lv), (uint32_t)(lu > lv ? lu : lv));
      }
    }
  }
}
// pointer jumping: plain loads/stores only (no atomics in this dispatch);
// races are benign (any observed value is a valid same-component label).
__global__ void k_jump(int* L, uint32_t* sc, int resetSlot, int liveSlot){
  int i = blockIdx.x*256 + threadIdx.x;
  if(i == 0) sc[resetSlot] = 0;
  if(sc[liveSlot] == 0) return;   // converged: skip node sweep
  if(i >= N_NODES) return;
  int v = L[i]; v = L[v]; v = L[v]; v = L[v];
  L[i] = v;
}
__global__ void k_cc_flatten(int* L, uint32_t* flags){
  int i = blockIdx.x*256 + threadIdx.x;
  if(i >= N_NODES) return;
  int p = L[i];
  int q = L[p];
  while(q != p){ p = q; q = L[p]; }
  L[i] = p;
  flags[i] = (p == i) ? 1u : 0u;
}

// ---- generic exclusive scan (2048 items/block). MODE 0: identity, static len. MODE 1: popc, len = sc[SC_W] ----
template<int MODE>
__global__ void k_scan_reduce(const uint32_t* in, uint32_t* bsums, const uint32_t* sc, uint32_t staticLen){
  uint32_t n = (MODE == 1) ? sc[SC_W] : staticLen;
  uint32_t base = blockIdx.x*2048u + threadIdx.x*8u;
  uint32_t s = 0;
  #pragma unroll
  for(int k = 0; k < 8; k++){
    uint32_t idx = base + k;
    if(idx < n){ uint32_t v = in[idx]; if(MODE == 1) v = __popc(v); s += v; }
  }
  __shared__ uint32_t sm[256];
  sm[threadIdx.x] = s; __syncthreads();
  for(int off = 128; off > 0; off >>= 1){
    if((int)threadIdx.x < off) sm[threadIdx.x] += sm[threadIdx.x + off];
    __syncthreads();
  }
  if(threadIdx.x == 0) bsums[blockIdx.x] = sm[0];
}
__global__ __launch_bounds__(1024) void k_scan_top(uint32_t* bsums, int nb, uint32_t* sc, int extras){
  __shared__ uint32_t sm[1024];
  int t = threadIdx.x;
  uint32_t xs[4]; uint32_t tsum = 0;
  #pragma unroll
  for(int k = 0; k < 4; k++){ int idx = t*4 + k; xs[k] = (idx < nb) ? bsums[idx] : 0u; tsum += xs[k]; }
  sm[t] = tsum; __syncthreads();
  for(int off = 1; off < 1024; off <<= 1){
    uint32_t y = (t >= off) ? sm[t - off] : 0u;
    __syncthreads(); sm[t] += y; __syncthreads();
  }
  uint32_t run = sm[t] - tsum;
  #pragma unroll
  for(int k = 0; k < 4; k++){ int idx = t*4 + k; if(idx < nb) bsums[idx] = run; run += xs[k]; }
  uint32_t total = sm[1023];
  if(t == 0){
    if(extras == 1){ sc[SC_C] = total; uint64_t cc = (uint64_t)total*(uint64_t)total; sc[SC_W] = (uint32_t)((cc + 31ull) >> 5); }
    else if(extras == 2){ sc[SC_U] = total; }
  }
}
template<int MODE>
__global__ void k_scan_apply(const uint32_t* in, const uint32_t* bsums, uint32_t* out, const uint32_t* sc, uint32_t staticLen){
  uint32_t n = (MODE == 1) ? sc[SC_W] : staticLen;
  uint32_t base = blockIdx.x*2048u + threadIdx.x*8u;
  uint32_t xs[8]; uint32_t tsum = 0;
  #pragma unroll
  for(int k = 0; k < 8; k++){
    uint32_t idx = base + k; uint32_t v = 0;
    if(idx < n){ v = in[idx]; if(MODE == 1) v = __popc(v); }
    xs[k] = v; tsum += v;
  }
  __shared__ uint32_t sm[256];
  sm[threadIdx.x] = tsum; __syncthreads();
  for(int off = 1; off < 256; off <<= 1){
    uint32_t y = ((int)threadIdx.x >= off) ? sm[threadIdx.x - off] : 0u;
    __syncthreads(); sm[threadIdx.x] += y; __syncthreads();
  }
  uint32_t run = bsums[blockIdx.x] + sm[threadIdx.x] - tsum;
  #pragma unroll
  for(int k = 0; k < 8; k++){ uint32_t idx = base + k; if(idx < n) out[idx] = run; run += xs[k]; }
}

// ---- cluster ids ----
__global__ void k_cluster(const int* labels, const uint32_t* rank_, int* cluster_i, float* outC){
  int i = blockIdx.x*256 + threadIdx.x;
  if(i >= N_NODES) return;
  int c = (int)rank_[labels[i]];
  cluster_i[i] = c;
  outC[i] = (float)c;
}

// ---- wave-aggregated counting (giant component would serialize naive atomics) ----
__global__ void k_counts(const int* cluster_i, uint32_t* counts){
  int i = blockIdx.x*256 + threadIdx.x;
  int lane = threadIdx.x & 63;
  int c = (i < N_NODES) ? cluster_i[i] : -1;
  unsigned long long remaining = __ballot(i < N_NODES);
  while(remaining){
    int leader = __ffsll(remaining) - 1;
    int lc = __shfl(c, leader);
    unsigned long long grp = __ballot(c == lc) & remaining;
    if(lane == leader) atomicAdd(&counts[lc], (uint32_t)__popcll(grp));
    remaining &= ~grp;
  }
}
__global__ void k_scatter(const int* cluster_i, uint32_t* cursor, uint32_t* order){
  int i = blockIdx.x*256 + threadIdx.x;
  int lane = threadIdx.x & 63;
  int c = (i < N_NODES) ? cluster_i[i] : -1;
  unsigned long long remaining = __ballot(i < N_NODES);
  while(remaining){
    int leader = __ffsll(remaining) - 1;
    int lc = __shfl(c, leader);
    unsigned long long grp = __ballot(c == lc) & remaining;
    int b = 0;
    if(lane == leader) b = (int)atomicAdd(&cursor[lc], (uint32_t)__popcll(grp));
    b = __shfl(b, leader);
    if((grp >> lane) & 1ull){
      uint32_t sub = (uint32_t)__popcll(grp & ((1ull << lane) - 1ull));
      order[(uint32_t)b + sub] = (uint32_t)i;
    }
    remaining &= ~grp;
  }
}

// ---- segmented mean over sorted-by-cluster order ----
__global__ void k_segsum(const float* px, const uint32_t* order, const int* cluster_i, float* outP){
  int wid = (int)((blockIdx.x*blockDim.x + threadIdx.x) >> 6);
  int lane = threadIdx.x & 63;
  int start = wid * SEG_CH;
  if(start >= N_NODES) return;
  int end = start + SEG_CH; if(end > N_NODES) end = N_NODES;
  float ax = 0.f, ay = 0.f; int cur = -1;
  for(int j = start; j < end; j++){
    uint32_t i = order[j];
    int c = cluster_i[i];
    if(c != cur){
      if(cur >= 0){
        atomicAdd(&outP[(size_t)cur*FDIM + 2*lane], ax);
        atomicAdd(&outP[(size_t)cur*FDIM + 2*lane + 1], ay);
      }
      cur = c; ax = 0.f; ay = 0.f;
    }
    const float2* row = (const float2*)(px + (size_t)i*FDIM);
    float2 v = row[lane];
    ax += v.x; ay += v.y;
  }
  if(cur >= 0){
    atomicAdd(&outP[(size_t)cur*FDIM + 2*lane], ax);
    atomicAdd(&outP[(size_t)cur*FDIM + 2*lane + 1], ay);
  }
}
__global__ void k_pnorm(const uint32_t* counts, float* outP){
  int nw = (gridDim.x*blockDim.x) >> 6;
  int wid = (int)((blockIdx.x*blockDim.x + threadIdx.x) >> 6);
  int lane = threadIdx.x & 63;
  for(int r = wid; r < N_NODES; r += nw){
    uint32_t cnt = counts[r];
    if(cnt > 1){
      float fc = (float)cnt;
      float2* row = (float2*)(outP + (size_t)r*FDIM);
      float2 v = row[lane]; v.x /= fc; v.y /= fc; row[lane] = v;
    }
  }
}

// ---- edges + pair keys ----
__global__ void k_edges(const int* src, const int* dst, const int* cluster_i, uint32_t* sc,
                        float* outE, uint32_t* kc, uint32_t* vlist){
  int e = blockIdx.x*256 + threadIdx.x;
  if(e >= N_EDGES) return;
  int cu = cluster_i[src[e]];
  int cv = cluster_i[dst[e]];
  bool val = (cu != cv);
  outE[e] = val ? (float)cu : -1.0f;
  outE[N_EDGES + e] = val ? (float)cv : -1.0f;
  if(val){
    int a = cu < cv ? cu : cv, b = cu < cv ? cv : cu;
    uint32_t C = sc[SC_C];
    kc[e] = (uint32_t)a * C + (uint32_t)b;
    uint32_t p = atomicAdd(&sc[SC_VCNT], 1u);
    vlist[p] = (uint32_t)e;
  } else {
    kc[e] = 0xFFFFFFFFu;
  }
}
__global__ void k_bitmap(const uint32_t* kc, uint32_t* bitmap){
  int e = blockIdx.x*256 + threadIdx.x;
  if(e >= N_EDGES) return;
  uint32_t k = kc[e];
  if(k != 0xFFFFFFFFu) atomicOr(&bitmap[k >> 5], 1u << (k & 31u));
}
__global__ void k_dualacc(const float* dx, const uint32_t* vlist, const uint32_t* kc,
                          const uint32_t* bitmap, const uint32_t* wpref, const uint32_t* sc,
                          float* outD, uint32_t* dcnt){
  int nw = (gridDim.x*blockDim.x) >> 6;
  int wid = (int)((blockIdx.x*blockDim.x + threadIdx.x) >> 6);
  int lane = threadIdx.x & 63;
  uint32_t vc = sc[SC_VCNT];
  for(uint32_t k = (uint32_t)wid; k < vc; k += (uint32_t)nw){
    uint32_t e = vlist[k];
    uint32_t kcv = kc[e];
    uint32_t wi = kcv >> 5, bi = kcv & 31u;
    uint32_t r = wpref[wi] + __popc(bitmap[wi] & ((1u << bi) - 1u));
    const float2* row = (const float2*)(dx + (size_t)e*FDIM);
    float2 v = row[lane];
    atomicAdd(&outD[(size_t)r*FDIM + 2*lane], v.x);
    atomicAdd(&outD[(size_t)r*FDIM + 2*lane + 1], v.y);
    if(lane == 0) atomicAdd(&dcnt[r], 1u);
  }
}
__global__ void k_dualnorm(const uint32_t* dcnt, const uint32_t* sc, float* outD){
  int nw = (gridDim.x*blockDim.x) >> 6;
  int wid = (int)((blockIdx.x*blockDim.x + threadIdx.x) >> 6);
  int lane = threadIdx.x & 63;
  uint32_t U = sc[SC_U];
  for(uint32_t r = (uint32_t)wid; r < U; r += (uint32_t)nw){
    uint32_t cnt = dcnt[r];
    if(cnt > 1){
      float fc = (float)cnt;
      float2* row = (float2*)(outD + (size_t)r*FDIM);
      float2 v = row[lane]; v.x /= fc; v.y /= fc; row[lane] = v;
    }
  }
}

extern "C" void kernel_launch(void* const* d_in, const int* in_sizes, int n_in,
                              void* d_out, int out_size, void* d_ws, size_t ws_size,
                              hipStream_t stream){
  (void)in_sizes; (void)n_in; (void)out_size;
  const float* primal_x = (const float*)d_in[0];
  const float* dual_x   = (const float*)d_in[1];
  const float* att      = (const float*)d_in[2];
  const int*   pei      = (const int*)d_in[3];
  const int* src = pei;
  const int* dst = pei + N_EDGES;

  float* out  = (float*)d_out;
  float* outP = out;                                    // (N, F) means
  float* outD = out + (size_t)N_NODES*FDIM;             // (E, F) dual means
  float* outE = outD + (size_t)N_EDGES*FDIM;            // (2, E) edge index (as float)
  float* outC = outE + (size_t)2*N_EDGES;               // (N,) cluster (as float)

  uint32_t* w = (uint32_t*)d_ws;
  size_t words_avail = ws_size / 4;
  const size_t FIXED = 64 + 65536 + 65536 + (size_t)N_NODES + (size_t)N_EDGES
                     + TIECAP + 6*(size_t)N_NODES + 4*(size_t)WLCAP
                     + 2*(size_t)N_EDGES + 4096;
  size_t wcap = (words_avail > FIXED) ? (words_avail - FIXED)/2 : 2;
  if(wcap > 8388608) wcap = 8388608;   // supports C up to 16384
  wcap &= ~(size_t)1;

  size_t o = 0;
  uint32_t* sc     = w;               o += 64;
  uint32_t* hist1  = w + o;           o += 65536;
  uint32_t* hist2  = w + o;           o += 65536;
  uint32_t* counts = w + o;           o += N_NODES;
  uint32_t* dcnt   = w + o;           o += N_EDGES;
  uint32_t* bitmap = w + o;           o += wcap;
  size_t zero_words = o;              // everything above zeroed per call
  uint32_t* tieIdx = w + o;           o += TIECAP;
  int* labels      = (int*)(w + o);   o += N_NODES;
  uint32_t* flags  = w + o;           o += N_NODES;
  uint32_t* rank_  = w + o;           o += N_NODES;
  uint32_t* cursor = w + o;           o += N_NODES;
  int* cluster_i   = (int*)(w + o);   o += N_NODES;
  uint32_t* order  = w + o;           o += N_NODES;
  uint2* wl0       = (uint2*)(w + o); o += 2*(size_t)WLCAP;
  uint2* wl1       = (uint2*)(w + o); o += 2*(size_t)WLCAP;
  uint32_t* kc     = w + o;           o += N_EDGES;
  uint32_t* vlist  = w + o;           o += N_EDGES;
  uint32_t* wpref  = w + o;           o += wcap;
  uint32_t* bsums  = w + o;           o += 4096;

  const int EB  = (N_EDGES + 255)/256;
  const int NB  = (N_NODES + 255)/256;
  const int NSB = (N_NODES + 2047)/2048;       // 98
  const int WSB = (int)((wcap + 2047)/2048);   // <= 4096

  hipMemsetAsync(out, 0, (size_t)(N_NODES + N_EDGES)*FDIM*sizeof(float), stream);
  hipMemsetAsync(w, 0, zero_words*sizeof(uint32_t), stream);

  // top-K selection
  k_hist1<<<EB,256,0,stream>>>(att, hist1);
  k_select_scan<<<1,1024,0,stream>>>(hist1, sc, 1);
  k_hist2<<<EB,256,0,stream>>>(att, hist2, sc);
  k_select_scan<<<1,1024,0,stream>>>(hist2, sc, 2);
  // CC: seed + worklist rounds
  k_cc_init<<<NB,256,0,stream>>>(labels);
  k_seed<<<EB,256,0,stream>>>(att, src, dst, sc, tieIdx, labels, wl0);
  k_tiesel<<<1,1024,0,stream>>>(sc, tieIdx, src, dst, labels, wl0);
  for(int r = 1; r <= CC_ROUNDS; ++r){
    int inSlot  = (r & 1) ? SC_WLA : SC_WLB;
    int outSlot = (r & 1) ? SC_WLB : SC_WLA;
    uint2* win  = (r & 1) ? wl0 : wl1;
    uint2* wout = (r & 1) ? wl1 : wl0;
    k_relax<<<1024,256,0,stream>>>(win, wout, labels, sc, inSlot, outSlot);
    k_jump<<<NB,256,0,stream>>>(labels, sc, inSlot, outSlot);
  }
  k_cc_flatten<<<NB,256,0,stream>>>(labels, flags);
  // compact labels -> cluster ids
  k_scan_reduce<0><<<NSB,256,0,stream>>>(flags, bsums, sc, N_NODES);
  k_scan_top<<<1,1024,0,stream>>>(bsums, NSB, sc, 1);
  k_scan_apply<0><<<NSB,256,0,stream>>>(flags, bsums, rank_, sc, N_NODES);
  k_cluster<<<NB,256,0,stream>>>(labels, rank_, cluster_i, outC);
  // primal mean via counting sort + contiguous segmented reduction
  k_counts<<<NB,256,0,stream>>>(cluster_i, counts);
  k_scan_reduce<0><<<NSB,256,0,stream>>>(counts, bsums, sc, N_NODES);
  k_scan_top<<<1,1024,0,stream>>>(bsums, NSB, sc, 0);
  k_scan_apply<0><<<NSB,256,0,stream>>>(counts, bsums, cursor, sc, N_NODES);
  k_scatter<<<NB,256,0,stream>>>(cluster_i, cursor, order);
  {
    int segw = (N_NODES + SEG_CH - 1)/SEG_CH;
    int segb = (segw + 3)/4;
    k_segsum<<<segb,256,0,stream>>>(primal_x, order, cluster_i, outP);
  }
  k_pnorm<<<512,256,0,stream>>>(counts, outP);
  // edges + dual-pair ranking via bitmap popcount-prefix
  k_edges<<<EB,256,0,stream>>>(src, dst, cluster_i, sc, outE, kc, vlist);
  k_bitmap<<<EB,256,0,stream>>>(kc, bitmap);
  k_scan_reduce<1><<<WSB,256,0,stream>>>(bitmap, bsums, sc, 0);
  k_scan_top<<<1,1024,0,stream>>>(bsums, WSB, sc, 2);
  k_scan_apply<1><<<WSB,256,0,stream>>>(bitmap, bsums, wpref, sc, 0);
  k_dualacc<<<1024,256,0,stream>>>(dual_x, vlist, kc, bitmap, wpref, sc, outD, dcnt);
  k_dualnorm<<<256,256,0,stream>>>(dcnt, sc, outD);
}

// Round 6
// 899.719 us; speedup vs baseline: 4.0663x; 1.3073x over previous
//
#include <hip/hip_runtime.h>
#include <stdint.h>

// DualPrimalEdgePooling on MI355X.
// Pipeline: 4-level 8-bit LDS radix-select -> worklist min-label CC
// (loop-free hooking relax + pointer-jump rounds, shrinking worklist) ->
// root-rank scan -> counting-sort segmented mean (primal) -> pair bitmap +
// popcount-prefix ranking (dual) -> dual mean.

#define N_NODES 200000
#define N_EDGES 600000
#define FDIM 128
#define NUM_POOL 300000u  // = E - NUM_KEEP: edges pooled (largest att)

#define SC_T 2        // threshold prefix accumulator (ordered u32)
#define SC_NEEDEQ 3   // remaining target within ties at threshold
#define SC_TIECNT 4
#define SC_C 5
#define SC_W 6
#define SC_U 7
#define SC_VCNT 8
#define SC_WLA 9
#define SC_WLB 10
#define TIECAP 4096
#define SEG_CH 128
#define WLCAP 300800
#define CC_ROUNDS 12
#define HB 256        // hist grid blocks

__device__ __forceinline__ uint32_t f2ou(float f){
  uint32_t b = __float_as_uint(f);
  return (b & 0x80000000u) ? ~b : (b | 0x80000000u);
}

// ---- selection: 4-level 8-bit radix select with LDS histograms ----
template<int LEVEL>
__global__ __launch_bounds__(256) void k_hist8(const float* att, uint32_t* sc, uint32_t* hist, int* L){
  __shared__ uint32_t h[256];
  h[threadIdx.x] = 0;
  if(LEVEL == 1){
    for(int i = blockIdx.x*256 + threadIdx.x; i < N_NODES; i += HB*256) L[i] = i;  // fused CC init
    if(blockIdx.x == 0 && threadIdx.x == 0) sc[SC_NEEDEQ] = NUM_POOL;              // init target
  }
  __syncthreads();
  uint32_t pfx = (LEVEL > 1) ? sc[SC_T] : 0u;
  for(int e = blockIdx.x*256 + threadIdx.x; e < N_EDGES; e += HB*256){
    uint32_t u = f2ou(att[e]);
    bool ok = (LEVEL == 1) || ((u >> (8*(5-LEVEL))) == pfx);
    if(ok) atomicAdd(&h[(u >> (8*(4-LEVEL))) & 0xFFu], 1u);
  }
  __syncthreads();
  uint32_t c = h[threadIdx.x];
  if(c) atomicAdd(&hist[threadIdx.x], c);
}
// pick digit: largest bins first; exactly one thread satisfies the window
__global__ __launch_bounds__(256) void k_sel8(uint32_t* hist, uint32_t* sc){
  __shared__ uint32_t sm[256];
  int t = threadIdx.x;
  uint32_t cnt = hist[t];
  hist[t] = 0;                       // reset for next level
  sm[t] = cnt; __syncthreads();
  for(int off = 1; off < 256; off <<= 1){
    uint32_t y = (t + off < 256) ? sm[t + off] : 0u;
    __syncthreads(); sm[t] += y; __syncthreads();
  }
  uint32_t target = sc[SC_NEEDEQ];
  uint32_t suffix = sm[t];           // count of candidates with digit >= t
  uint32_t above  = suffix - cnt;    // strictly greater digits
  if(above < target && target <= suffix){
    sc[SC_T] = (sc[SC_T] << 8) | (uint32_t)t;
    sc[SC_NEEDEQ] = target - above;
  }
}

// ---- CC: seed (selection fused), loop-free relax rounds, jump, flatten ----
// pooled edges (att > T): seed atomicMin + append to worklist; ties recorded
__global__ void k_seed(const float* att, const int* src, const int* dst, uint32_t* sc,
                       uint32_t* tieIdx, int* L, uint2* wl){
  int e = blockIdx.x*256 + threadIdx.x;
  int lane = threadIdx.x & 63;
  bool app = false; int u = 0, v = 0;
  if(e < N_EDGES){
    uint32_t T = sc[SC_T];
    uint32_t ub = f2ou(att[e]);
    if(ub > T){
      u = src[e]; v = dst[e];
      if(u != v){
        int m = u < v ? u : v, hi = u ^ v ^ m;
        atomicMin(&L[hi], m);
        app = true;
      }
    } else if(ub == T){
      uint32_t p = atomicAdd(&sc[SC_TIECNT], 1u);
      if(p < TIECAP) tieIdx[p] = (uint32_t)e;
    }
  }
  unsigned long long grp = __ballot(app);
  if(grp){
    int leader = __ffsll(grp) - 1;
    uint32_t base = 0;
    if(lane == leader) base = atomicAdd(&sc[SC_WLA], (uint32_t)__popcll(grp));
    base = (uint32_t)__shfl((int)base, leader);
    if(app){
      uint32_t off = (uint32_t)__popcll(grp & ((1ull << lane) - 1ull));
      wl[base + off] = make_uint2((uint32_t)(u < v ? u : v), (uint32_t)(u > v ? u : v));
    }
  }
}
__global__ __launch_bounds__(1024) void k_tiesel(uint32_t* sc, const uint32_t* tieIdx,
                        const int* src, const int* dst, int* L, uint2* wl){
  uint32_t m = sc[SC_TIECNT]; if(m > TIECAP) m = TIECAP;
  uint32_t need = sc[SC_NEEDEQ];
  int lane = threadIdx.x & 63;
  for(uint32_t i0 = 0; i0 < m; i0 += 1024){
    uint32_t i = i0 + threadIdx.x;
    bool app = false; int u = 0, v = 0;
    if(i < m){
      uint32_t mine = tieIdx[i];
      uint32_t r = 0;
      for(uint32_t j = 0; j < m; j++) r += (tieIdx[j] < mine) ? 1u : 0u;
      if(r < need){   // stable argsort: smallest indices pooled
        u = src[mine]; v = dst[mine];
        if(u != v){ int mm = u < v ? u : v, hi = u ^ v ^ mm; atomicMin(&L[hi], mm); app = true; }
      }
    }
    unsigned long long grp = __ballot(app);
    if(grp){
      int leader = __ffsll(grp) - 1;
      uint32_t base = 0;
      if(lane == leader) base = atomicAdd(&sc[SC_WLA], (uint32_t)__popcll(grp));
      base = (uint32_t)__shfl((int)base, leader);
      if(app){
        uint32_t off = (uint32_t)__popcll(grp & ((1ull << lane) - 1ull));
        wl[base + off] = make_uint2((uint32_t)(u < v ? u : v), (uint32_t)(u > v ? u : v));
      }
    }
  }
}
// loop-free relax: 3-level chase (plain loads), one-shot hooking atomicMin,
// survivors re-appended. Stale reads are >= true value (monotone) => safe.
__global__ __launch_bounds__(256) void k_relax(const uint2* wl_in, uint2* wl_out, int* L,
                       uint32_t* sc, int inSlot, int outSlot){
  uint32_t n = sc[inSlot];
  int lane = threadIdx.x & 63;
  for(uint32_t base = blockIdx.x*256u; base < n; base += gridDim.x*256u){
    uint32_t idx = base + threadIdx.x;
    bool active = idx < n;
    int lu = 0, lv = 0;
    if(active){
      uint2 ed = wl_in[idx];
      lu = L[ed.x]; lu = L[lu]; lu = L[lu];
      lv = L[ed.y]; lv = L[lv]; lv = L[lv];
      active = (lu != lv);
      if(active){
        int m = lu < lv ? lu : lv, hi = lu ^ lv ^ m;
        atomicMin(&L[hi], m);
      }
    }
    unsigned long long grp = __ballot(active);
    if(grp){
      int leader = __ffsll(grp) - 1;
      uint32_t b = 0;
      if(lane == leader) b = atomicAdd(&sc[outSlot], (uint32_t)__popcll(grp));
      b = (uint32_t)__shfl((int)b, leader);
      if(active){
        uint32_t off = (uint32_t)__popcll(grp & ((1ull << lane) - 1ull));
        wl_out[b + off] = make_uint2((uint32_t)(lu < lv ? lu : lv), (uint32_t)(lu > lv ? lu : lv));
      }
    }
  }
}
// pointer jumping: plain loads/stores only (no atomics in this dispatch);
// races are benign (any observed value is a valid same-component label).
__global__ void k_jump(int* L, uint32_t* sc, int resetSlot, int liveSlot){
  int i = blockIdx.x*256 + threadIdx.x;
  if(i == 0) sc[resetSlot] = 0;
  if(sc[liveSlot] == 0) return;   // converged: skip node sweep
  if(i >= N_NODES) return;
  int v = L[i]; v = L[v]; v = L[v]; v = L[v];
  L[i] = v;
}
__global__ void k_cc_flatten(int* L, uint32_t* flags){
  int i = blockIdx.x*256 + threadIdx.x;
  if(i >= N_NODES) return;
  int p = L[i];
  int q = L[p];
  while(q != p){ p = q; q = L[p]; }
  L[i] = p;
  flags[i] = (p == i) ? 1u : 0u;
}

// ---- generic exclusive scan (2048 items/block). MODE 0: identity, static len. MODE 1: popc, len = sc[SC_W] ----
template<int MODE>
__global__ void k_scan_reduce(const uint32_t* in, uint32_t* bsums, const uint32_t* sc, uint32_t staticLen){
  uint32_t n = (MODE == 1) ? sc[SC_W] : staticLen;
  uint32_t base = blockIdx.x*2048u + threadIdx.x*8u;
  uint32_t s = 0;
  #pragma unroll
  for(int k = 0; k < 8; k++){
    uint32_t idx = base + k;
    if(idx < n){ uint32_t v = in[idx]; if(MODE == 1) v = __popc(v); s += v; }
  }
  __shared__ uint32_t sm[256];
  sm[threadIdx.x] = s; __syncthreads();
  for(int off = 128; off > 0; off >>= 1){
    if((int)threadIdx.x < off) sm[threadIdx.x] += sm[threadIdx.x + off];
    __syncthreads();
  }
  if(threadIdx.x == 0) bsums[blockIdx.x] = sm[0];
}
__global__ __launch_bounds__(1024) void k_scan_top(uint32_t* bsums, int nb, uint32_t* sc, int extras){
  __shared__ uint32_t sm[1024];
  int t = threadIdx.x;
  uint32_t xs[4]; uint32_t tsum = 0;
  #pragma unroll
  for(int k = 0; k < 4; k++){ int idx = t*4 + k; xs[k] = (idx < nb) ? bsums[idx] : 0u; tsum += xs[k]; }
  sm[t] = tsum; __syncthreads();
  for(int off = 1; off < 1024; off <<= 1){
    uint32_t y = (t >= off) ? sm[t - off] : 0u;
    __syncthreads(); sm[t] += y; __syncthreads();
  }
  uint32_t run = sm[t] - tsum;
  #pragma unroll
  for(int k = 0; k < 4; k++){ int idx = t*4 + k; if(idx < nb) bsums[idx] = run; run += xs[k]; }
  uint32_t total = sm[1023];
  if(t == 0){
    if(extras == 1){ sc[SC_C] = total; uint64_t cc = (uint64_t)total*(uint64_t)total; sc[SC_W] = (uint32_t)((cc + 31ull) >> 5); }
    else if(extras == 2){ sc[SC_U] = total; }
  }
}
template<int MODE>
__global__ void k_scan_apply(const uint32_t* in, const uint32_t* bsums, uint32_t* out, const uint32_t* sc, uint32_t staticLen){
  uint32_t n = (MODE == 1) ? sc[SC_W] : staticLen;
  uint32_t base = blockIdx.x*2048u + threadIdx.x*8u;
  uint32_t xs[8]; uint32_t tsum = 0;
  #pragma unroll
  for(int k = 0; k < 8; k++){
    uint32_t idx = base + k; uint32_t v = 0;
    if(idx < n){ v = in[idx]; if(MODE == 1) v = __popc(v); }
    xs[k] = v; tsum += v;
  }
  __shared__ uint32_t sm[256];
  sm[threadIdx.x] = tsum; __syncthreads();
  for(int off = 1; off < 256; off <<= 1){
    uint32_t y = ((int)threadIdx.x >= off) ? sm[threadIdx.x - off] : 0u;
    __syncthreads(); sm[threadIdx.x] += y; __syncthreads();
  }
  uint32_t run = bsums[blockIdx.x] + sm[threadIdx.x] - tsum;
  #pragma unroll
  for(int k = 0; k < 8; k++){ uint32_t idx = base + k; if(idx < n) out[idx] = run; run += xs[k]; }
}

// ---- cluster ids ----
__global__ void k_cluster(const int* labels, const uint32_t* rank_, int* cluster_i, float* outC){
  int i = blockIdx.x*256 + threadIdx.x;
  if(i >= N_NODES) return;
  int c = (int)rank_[labels[i]];
  cluster_i[i] = c;
  outC[i] = (float)c;
}

// ---- wave-aggregated counting (giant component would serialize naive atomics) ----
__global__ void k_counts(const int* cluster_i, uint32_t* counts){
  int i = blockIdx.x*256 + threadIdx.x;
  int lane = threadIdx.x & 63;
  int c = (i < N_NODES) ? cluster_i[i] : -1;
  unsigned long long remaining = __ballot(i < N_NODES);
  while(remaining){
    int leader = __ffsll(remaining) - 1;
    int lc = __shfl(c, leader);
    unsigned long long grp = __ballot(c == lc) & remaining;
    if(lane == leader) atomicAdd(&counts[lc], (uint32_t)__popcll(grp));
    remaining &= ~grp;
  }
}
__global__ void k_scatter(const int* cluster_i, uint32_t* cursor, uint32_t* order){
  int i = blockIdx.x*256 + threadIdx.x;
  int lane = threadIdx.x & 63;
  int c = (i < N_NODES) ? cluster_i[i] : -1;
  unsigned long long remaining = __ballot(i < N_NODES);
  while(remaining){
    int leader = __ffsll(remaining) - 1;
    int lc = __shfl(c, leader);
    unsigned long long grp = __ballot(c == lc) & remaining;
    int b = 0;
    if(lane == leader) b = (int)atomicAdd(&cursor[lc], (uint32_t)__popcll(grp));
    b = __shfl(b, leader);
    if((grp >> lane) & 1ull){
      uint32_t sub = (uint32_t)__popcll(grp & ((1ull << lane) - 1ull));
      order[(uint32_t)b + sub] = (uint32_t)i;
    }
    remaining &= ~grp;
  }
}

// ---- segmented mean over sorted-by-cluster order ----
__global__ void k_segsum(const float* px, const uint32_t* order, const int* cluster_i, float* outP){
  int wid = (int)((blockIdx.x*blockDim.x + threadIdx.x) >> 6);
  int lane = threadIdx.x & 63;
  int start = wid * SEG_CH;
  if(start >= N_NODES) return;
  int end = start + SEG_CH; if(end > N_NODES) end = N_NODES;
  float ax = 0.f, ay = 0.f; int cur = -1;
  for(int j = start; j < end; j++){
    uint32_t i = order[j];
    int c = cluster_i[i];
    if(c != cur){
      if(cur >= 0){
        atomicAdd(&outP[(size_t)cur*FDIM + 2*lane], ax);
        atomicAdd(&outP[(size_t)cur*FDIM + 2*lane + 1], ay);
      }
      cur = c; ax = 0.f; ay = 0.f;
    }
    const float2* row = (const float2*)(px + (size_t)i*FDIM);
    float2 v = row[lane];
    ax += v.x; ay += v.y;
  }
  if(cur >= 0){
    atomicAdd(&outP[(size_t)cur*FDIM + 2*lane], ax);
    atomicAdd(&outP[(size_t)cur*FDIM + 2*lane + 1], ay);
  }
}
__global__ void k_pnorm(const uint32_t* counts, float* outP){
  int nw = (gridDim.x*blockDim.x) >> 6;
  int wid = (int)((blockIdx.x*blockDim.x + threadIdx.x) >> 6);
  int lane = threadIdx.x & 63;
  for(int r = wid; r < N_NODES; r += nw){
    uint32_t cnt = counts[r];
    if(cnt > 1){
      float fc = (float)cnt;
      float2* row = (float2*)(outP + (size_t)r*FDIM);
      float2 v = row[lane]; v.x /= fc; v.y /= fc; row[lane] = v;
    }
  }
}

// ---- edges + pair keys ----
__global__ void k_edges(const int* src, const int* dst, const int* cluster_i, uint32_t* sc,
                        float* outE, uint32_t* kc, uint32_t* vlist){
  int e = blockIdx.x*256 + threadIdx.x;
  if(e >= N_EDGES) return;
  int cu = cluster_i[src[e]];
  int cv = cluster_i[dst[e]];
  bool val = (cu != cv);
  outE[e] = val ? (float)cu : -1.0f;
  outE[N_EDGES + e] = val ? (float)cv : -1.0f;
  if(val){
    int a = cu < cv ? cu : cv, b = cu < cv ? cv : cu;
    uint32_t C = sc[SC_C];
    kc[e] = (uint32_t)a * C + (uint32_t)b;
    uint32_t p = atomicAdd(&sc[SC_VCNT], 1u);
    vlist[p] = (uint32_t)e;
  } else {
    kc[e] = 0xFFFFFFFFu;
  }
}
__global__ void k_bitmap(const uint32_t* kc, uint32_t* bitmap){
  int e = blockIdx.x*256 + threadIdx.x;
  if(e >= N_EDGES) return;
  uint32_t k = kc[e];
  if(k != 0xFFFFFFFFu) atomicOr(&bitmap[k >> 5], 1u << (k & 31u));
}
__global__ void k_dualacc(const float* dx, const uint32_t* vlist, const uint32_t* kc,
                          const uint32_t* bitmap, const uint32_t* wpref, const uint32_t* sc,
                          float* outD, uint32_t* dcnt){
  int nw = (gridDim.x*blockDim.x) >> 6;
  int wid = (int)((blockIdx.x*blockDim.x + threadIdx.x) >> 6);
  int lane = threadIdx.x & 63;
  uint32_t vc = sc[SC_VCNT];
  for(uint32_t k = (uint32_t)wid; k < vc; k += (uint32_t)nw){
    uint32_t e = vlist[k];
    uint32_t kcv = kc[e];
    uint32_t wi = kcv >> 5, bi = kcv & 31u;
    uint32_t r = wpref[wi] + __popc(bitmap[wi] & ((1u << bi) - 1u));
    const float2* row = (const float2*)(dx + (size_t)e*FDIM);
    float2 v = row[lane];
    atomicAdd(&outD[(size_t)r*FDIM + 2*lane], v.x);
    atomicAdd(&outD[(size_t)r*FDIM + 2*lane + 1], v.y);
    if(lane == 0) atomicAdd(&dcnt[r], 1u);
  }
}
__global__ void k_dualnorm(const uint32_t* dcnt, const uint32_t* sc, float* outD){
  int nw = (gridDim.x*blockDim.x) >> 6;
  int wid = (int)((blockIdx.x*blockDim.x + threadIdx.x) >> 6);
  int lane = threadIdx.x & 63;
  uint32_t U = sc[SC_U];
  for(uint32_t r = (uint32_t)wid; r < U; r += (uint32_t)nw){
    uint32_t cnt = dcnt[r];
    if(cnt > 1){
      float fc = (float)cnt;
      float2* row = (float2*)(outD + (size_t)r*FDIM);
      float2 v = row[lane]; v.x /= fc; v.y /= fc; row[lane] = v;
    }
  }
}

extern "C" void kernel_launch(void* const* d_in, const int* in_sizes, int n_in,
                              void* d_out, int out_size, void* d_ws, size_t ws_size,
                              hipStream_t stream){
  (void)in_sizes; (void)n_in; (void)out_size;
  const float* primal_x = (const float*)d_in[0];
  const float* dual_x   = (const float*)d_in[1];
  const float* att      = (const float*)d_in[2];
  const int*   pei      = (const int*)d_in[3];
  const int* src = pei;
  const int* dst = pei + N_EDGES;

  float* out  = (float*)d_out;
  float* outP = out;                                    // (N, F) means
  float* outD = out + (size_t)N_NODES*FDIM;             // (E, F) dual means
  float* outE = outD + (size_t)N_EDGES*FDIM;            // (2, E) edge index (as float)
  float* outC = outE + (size_t)2*N_EDGES;               // (N,) cluster (as float)

  uint32_t* w = (uint32_t*)d_ws;
  size_t words_avail = ws_size / 4;
  const size_t FIXED = 64 + 256 + (size_t)N_NODES + (size_t)N_EDGES
                     + TIECAP + 6*(size_t)N_NODES + 4*(size_t)WLCAP
                     + 2*(size_t)N_EDGES + 4096;
  size_t wcap = (words_avail > FIXED) ? (words_avail - FIXED)/2 : 2;
  if(wcap > 8388608) wcap = 8388608;   // supports C up to 16384
  wcap &= ~(size_t)1;

  size_t o = 0;
  uint32_t* sc     = w;               o += 64;
  uint32_t* hist8  = w + o;           o += 256;
  uint32_t* counts = w + o;           o += N_NODES;
  uint32_t* dcnt   = w + o;           o += N_EDGES;
  uint32_t* bitmap = w + o;           o += wcap;
  size_t zero_words = o;              // everything above zeroed per call
  uint32_t* tieIdx = w + o;           o += TIECAP;
  int* labels      = (int*)(w + o);   o += N_NODES;
  uint32_t* flags  = w + o;           o += N_NODES;
  uint32_t* rank_  = w + o;           o += N_NODES;
  uint32_t* cursor = w + o;           o += N_NODES;
  int* cluster_i   = (int*)(w + o);   o += N_NODES;
  uint32_t* order  = w + o;           o += N_NODES;
  uint2* wl0       = (uint2*)(w + o); o += 2*(size_t)WLCAP;
  uint2* wl1       = (uint2*)(w + o); o += 2*(size_t)WLCAP;
  uint32_t* kc     = w + o;           o += N_EDGES;
  uint32_t* vlist  = w + o;           o += N_EDGES;
  uint32_t* wpref  = w + o;           o += wcap;
  uint32_t* bsums  = w + o;           o += 4096;

  const int EB  = (N_EDGES + 255)/256;
  const int NB  = (N_NODES + 255)/256;
  const int NSB = (N_NODES + 2047)/2048;       // 98
  const int WSB = (int)((wcap + 2047)/2048);   // <= 4096

  hipMemsetAsync(out, 0, (size_t)(N_NODES + N_EDGES)*FDIM*sizeof(float), stream);
  hipMemsetAsync(w, 0, zero_words*sizeof(uint32_t), stream);

  // top-K selection: 4-level 8-bit radix select (LDS hists; CC init fused in L1)
  int* labels_p = labels;
  k_hist8<1><<<HB,256,0,stream>>>(att, sc, hist8, labels_p);
  k_sel8<<<1,256,0,stream>>>(hist8, sc);
  k_hist8<2><<<HB,256,0,stream>>>(att, sc, hist8, labels_p);
  k_sel8<<<1,256,0,stream>>>(hist8, sc);
  k_hist8<3><<<HB,256,0,stream>>>(att, sc, hist8, labels_p);
  k_sel8<<<1,256,0,stream>>>(hist8, sc);
  k_hist8<4><<<HB,256,0,stream>>>(att, sc, hist8, labels_p);
  k_sel8<<<1,256,0,stream>>>(hist8, sc);
  // CC: seed + worklist rounds
  k_seed<<<EB,256,0,stream>>>(att, src, dst, sc, tieIdx, labels, wl0);
  k_tiesel<<<1,1024,0,stream>>>(sc, tieIdx, src, dst, labels, wl0);
  for(int r = 1; r <= CC_ROUNDS; ++r){
    int inSlot  = (r & 1) ? SC_WLA : SC_WLB;
    int outSlot = (r & 1) ? SC_WLB : SC_WLA;
    uint2* win  = (r & 1) ? wl0 : wl1;
    uint2* wout = (r & 1) ? wl1 : wl0;
    k_relax<<<1024,256,0,stream>>>(win, wout, labels, sc, inSlot, outSlot);
    k_jump<<<NB,256,0,stream>>>(labels, sc, inSlot, outSlot);
  }
  k_cc_flatten<<<NB,256,0,stream>>>(labels, flags);
  // compact labels -> cluster ids
  k_scan_reduce<0><<<NSB,256,0,stream>>>(flags, bsums, sc, N_NODES);
  k_scan_top<<<1,1024,0,stream>>>(bsums, NSB, sc, 1);
  k_scan_apply<0><<<NSB,256,0,stream>>>(flags, bsums, rank_, sc, N_NODES);
  k_cluster<<<NB,256,0,stream>>>(labels, rank_, cluster_i, outC);
  // primal mean via counting sort + contiguous segmented reduction
  k_counts<<<NB,256,0,stream>>>(cluster_i, counts);
  k_scan_reduce<0><<<NSB,256,0,stream>>>(counts, bsums, sc, N_NODES);
  k_scan_top<<<1,1024,0,stream>>>(bsums, NSB, sc, 0);
  k_scan_apply<0><<<NSB,256,0,stream>>>(counts, bsums, cursor, sc, N_NODES);
  k_scatter<<<NB,256,0,stream>>>(cluster_i, cursor, order);
  {
    int segw = (N_NODES + SEG_CH - 1)/SEG_CH;
    int segb = (segw + 3)/4;
    k_segsum<<<segb,256,0,stream>>>(primal_x, order, cluster_i, outP);
  }
  k_pnorm<<<512,256,0,stream>>>(counts, outP);
  // edges + dual-pair ranking via bitmap popcount-prefix
  k_edges<<<EB,256,0,stream>>>(src, dst, cluster_i, sc, outE, kc, vlist);
  k_bitmap<<<EB,256,0,stream>>>(kc, bitmap);
  k_scan_reduce<1><<<WSB,256,0,stream>>>(bitmap, bsums, sc, 0);
  k_scan_top<<<1,1024,0,stream>>>(bsums, WSB, sc, 2);
  k_scan_apply<1><<<WSB,256,0,stream>>>(bitmap, bsums, wpref, sc, 0);
  k_dualacc<<<1024,256,0,stream>>>(dual_x, vlist, kc, bitmap, wpref, sc, outD, dcnt);
  k_dualnorm<<<256,256,0,stream>>>(dcnt, sc, outD);
}